// Round 6
// baseline (516.032 us; speedup 1.0000x reference)
//
#include <hip/hip_runtime.h>

typedef __attribute__((ext_vector_type(8))) short bf16x8;
typedef __attribute__((ext_vector_type(4))) float f32x4;
typedef unsigned int u32;
typedef unsigned short u16;

constexpr int Bb = 4, S = 2048, D = 1024, H = 16, DK = 64, M = Bb * S;

#if __has_builtin(__builtin_amdgcn_exp2f)
#define EXP2F __builtin_amdgcn_exp2f
#else
#define EXP2F exp2f
#endif

__device__ __forceinline__ u16 f2bf(float f) {
  u32 u = __float_as_uint(f);
  return (u16)((u + 0x7fffu + ((u >> 16) & 1u)) >> 16);
}

__device__ __forceinline__ void gld_lds16(const u16* g, u16* l) {
  __builtin_amdgcn_global_load_lds((const __attribute__((address_space(1))) u32*)g,
                                   (__attribute__((address_space(3))) u32*)l, 16, 0, 0);
}

__global__ void cast_kernel(const float* __restrict__ s, u16* __restrict__ d, int n) {
  int i = (blockIdx.x * blockDim.x + threadIdx.x) * 4;
  if (i >= n) return;
  float4 f = *(const float4*)(s + i);
  ushort4 o;
  o.x = f2bf(f.x); o.y = f2bf(f.y); o.z = f2bf(f.z); o.w = f2bf(f.w);
  *(ushort4*)(d + i) = o;
}

struct CastArgs { const float* s[4]; u16* d[4]; float sc[4]; };
__global__ void cast4_kernel(CastArgs a) {
  int i = (blockIdx.x * blockDim.x + threadIdx.x) * 4;
  int w = i >> 20;
  int off = i & ((1 << 20) - 1);
  float sc = a.sc[w];
  float4 f = *(const float4*)(a.s[w] + off);
  ushort4 o;
  o.x = f2bf(f.x * sc); o.y = f2bf(f.y * sc); o.z = f2bf(f.z * sc); o.w = f2bf(f.w * sc);
  *(ushort4*)(a.d[w] + off) = o;
}

// ---- GEMM core: C[m,n] = sum_k A[m,k]*Bt[n,k], 128x128 tile, BK=64 ----
template <bool OUTF32>
__device__ __forceinline__ void gemm_core(const u16* __restrict__ A,
                                          const u16* __restrict__ Bt,
                                          float* __restrict__ Cf, u16* __restrict__ Cb,
                                          int Nn, int Kk, int m0, int n0,
                                          u16* As, u16* Bs) {
  const int tid = threadIdx.x, wave = tid >> 6, lane = tid & 63;
  const int quad = lane >> 4, col = lane & 15;
  const int wm = wave >> 1, wn = wave & 1;

  f32x4 acc[4][4];
#pragma unroll
  for (int i = 0; i < 4; i++)
#pragma unroll
    for (int j = 0; j < 4; j++) acc[i][j] = (f32x4){0.f, 0.f, 0.f, 0.f};

  for (int k0 = 0; k0 < Kk; k0 += 64) {
#pragma unroll
    for (int j = 0; j < 4; j++) {
      int g = (wave * 4 + j) * 64;
      int gl = g + lane;
      int r = gl >> 3, sl = gl & 7;
      int kof = (sl ^ (r & 7)) * 8;
      const u16* ga = A + (size_t)(m0 + r) * Kk + k0 + kof;
      gld_lds16(ga, &As[g * 8]);
      const u16* gb = Bt + (size_t)(n0 + r) * Kk + k0 + kof;
      gld_lds16(gb, &Bs[g * 8]);
    }
    __syncthreads();
#pragma unroll
    for (int kb = 0; kb < 2; kb++) {
      bf16x8 af[4], bfr[4];
#pragma unroll
      for (int mi = 0; mi < 4; mi++) {
        int R = wm * 64 + mi * 16 + col;
        af[mi] = *(const bf16x8*)&As[R * 64 + (((kb * 4 + quad) ^ (R & 7)) << 3)];
      }
#pragma unroll
      for (int ni = 0; ni < 4; ni++) {
        int R = wn * 64 + ni * 16 + col;
        bfr[ni] = *(const bf16x8*)&Bs[R * 64 + (((kb * 4 + quad) ^ (R & 7)) << 3)];
      }
#pragma unroll
      for (int mi = 0; mi < 4; mi++)
#pragma unroll
        for (int ni = 0; ni < 4; ni++)
          acc[mi][ni] = __builtin_amdgcn_mfma_f32_16x16x32_bf16(af[mi], bfr[ni], acc[mi][ni], 0, 0, 0);
    }
    __syncthreads();
  }
#pragma unroll
  for (int mi = 0; mi < 4; mi++)
#pragma unroll
    for (int ni = 0; ni < 4; ni++)
#pragma unroll
      for (int r = 0; r < 4; r++) {
        int row = m0 + wm * 64 + mi * 16 + quad * 4 + r;
        int cc = n0 + wn * 64 + ni * 16 + col;
        float v = acc[mi][ni][r];
        if (OUTF32) Cf[(size_t)row * Nn + cc] = v;
        else Cb[(size_t)row * Nn + cc] = f2bf(v);
      }
}

struct QkvArgs { const u16* bt[3]; u16* c[3]; };
__global__ __launch_bounds__(256) void gemm_qkv(const u16* __restrict__ A, QkvArgs q) {
  __shared__ __align__(16) u16 As[128 * 64];
  __shared__ __align__(16) u16 Bs[128 * 64];
  int sel = blockIdx.x >> 3;
  int n0 = (blockIdx.x & 7) * 128, m0 = blockIdx.y * 128;
  gemm_core<false>(A, q.bt[sel], nullptr, q.c[sel], D, D, m0, n0, As, Bs);
}

__global__ __launch_bounds__(256) void gemm_f32(const u16* __restrict__ A,
                                                const u16* __restrict__ Bt,
                                                float* __restrict__ C) {
  __shared__ __align__(16) u16 As[128 * 64];
  __shared__ __align__(16) u16 Bs[128 * 64];
  gemm_core<true>(A, Bt, C, nullptr, D, D, blockIdx.y * 128, blockIdx.x * 128, As, Bs);
}

// ---- flash attention, causal ----
// One 128-row q-block per workgroup; grid (64 bh, 16) = 1024 blocks = 4/CU.
// y->qb map {a,7-a,8+a,15-a} balances every CU's 4-block bundle at 68 iters.
// LDS 40KB (Ks dbuf 16K + Vt dbuf 16K + per-wave per-mi Pw 8K) -> 4 blocks/CU.
// VGPR capped at 128 via __launch_bounds__(256,4).
// K double-buffered via global_load_lds DMA prefetched right after the
// barrier; V double-buffered regs->LDS transposed+swizzled (u32 writes).
// Q pre-scaled by 0.125*log2e => p = exp2(sacc); trunc-store bf16 P;
// row sums via ones-MFMA.
__global__ __launch_bounds__(256, 4) void attn_kernel(const u16* __restrict__ Q,
                                                      const u16* __restrict__ K,
                                                      const u16* __restrict__ V,
                                                      u16* __restrict__ O) {
  __shared__ __align__(16) u16 Ks[2][2][64 * 32];  // [buf][d-half][key*32+d]
  __shared__ __align__(16) u16 Vt[2][64 * 64];     // [buf] V^T [d][key-swizzled]
  __shared__ __align__(16) u16 Pw[4][16 * 64];     // per-wave per-mi P [q16][key-swz]
  const int tid = threadIdx.x, wave = tid >> 6, lane = tid & 63;
  const int quad = lane >> 4, col = lane & 15;
  const int bh = blockIdx.x, b = bh >> 4, h = bh & 15;
  const int ya = blockIdx.y & 3, yk = blockIdx.y >> 2;
  const int qb = (yk == 0) ? ya : (yk == 1) ? 7 - ya : (yk == 2) ? 8 + ya : 15 - ya;
  const size_t base = (size_t)b * S * D + h * DK;
  const int qw = qb * 128 + wave * 32;
  const int nkt = 2 * qb + 2;  // >= 2

  bf16x8 aq[2][2];
#pragma unroll
  for (int mi = 0; mi < 2; mi++)
#pragma unroll
    for (int kb = 0; kb < 2; kb++)
      aq[mi][kb] = *(const bf16x8*)(Q + base + (size_t)(qw + mi * 16 + col) * D + kb * 32 + quad * 8);

  f32x4 ao[2][4], lacc[2];
#pragma unroll
  for (int mi = 0; mi < 2; mi++) {
    lacc[mi] = (f32x4){0.f, 0.f, 0.f, 0.f};
#pragma unroll
    for (int dg = 0; dg < 4; dg++) ao[mi][dg] = (f32x4){0.f, 0.f, 0.f, 0.f};
  }
  bf16x8 bones;
#pragma unroll
  for (int e = 0; e < 8; e++) bones[e] = (short)0x3F80;  // bf16 1.0

  // V staging: thread handles keys (vk0, vk0+1) x 8 d's; packed u32 writes
  const int vk0 = (tid & 31) * 2;
  const int vdg = tid >> 5;

  bf16x8 vA0, vA1, vB0, vB1;
  {
    const u16* vp = V + base + (size_t)vk0 * D + vdg * 8;
    vA0 = *(const bf16x8*)vp; vA1 = *(const bf16x8*)(vp + D);
  }
  {  // DMA K(0) -> Ks[0]
    int c = tid, cb = wave * 64;
    const u16* g0 = K + base + (size_t)(c >> 2) * D + (c & 3) * 8;
    gld_lds16(g0, &Ks[0][0][cb * 8]);
    gld_lds16(g0 + 32, &Ks[0][1][cb * 8]);
  }
  auto vstage = [&](int buf, bf16x8 r0, bf16x8 r1) {
    int kgrp = vk0 >> 3, kin = vk0 & 7;
    int perm = (kgrp ^ vdg) & 7;
#pragma unroll
    for (int e = 0; e < 8; e++) {
      u32 val = ((u32)(u16)r0[e]) | ((u32)(u16)r1[e] << 16);
      *(u32*)&Vt[buf][(vdg * 8 + e) * 64 + perm * 8 + kin] = val;
    }
  };
  vstage(0, vA0, vA1);
  {  // V(1) -> B regs
    const u16* vp = V + base + (size_t)(64 + vk0) * D + vdg * 8;
    vB0 = *(const bf16x8*)vp; vB1 = *(const bf16x8*)(vp + D);
  }

  for (int kt = 0; kt < nkt; kt++) {
    const int bf = kt & 1, nb = bf ^ 1, ph = kt & 1;
    __syncthreads();  // drains K(kt) DMA + V(kt+1) regs; publishes Vt[bf]
    const bool active = (kt * 64 <= qw + 31);  // wave-uniform
    if (kt + 1 < nkt) {
      {  // prefetch K(kt+1) -> Ks[nb] (a full iteration to land)
        int c = tid, cb = wave * 64;
        const u16* g0 = K + base + (size_t)((kt + 1) * 64 + (c >> 2)) * D + (c & 3) * 8;
        gld_lds16(g0, &Ks[nb][0][cb * 8]);
        gld_lds16(g0 + 32, &Ks[nb][1][cb * 8]);
      }
      vstage(nb, ph ? vA0 : vB0, ph ? vA1 : vB1);
      if (kt + 2 < nkt) {
        const u16* vp = V + base + (size_t)((kt + 2) * 64 + vk0) * D + vdg * 8;
        if (ph) { vB0 = *(const bf16x8*)vp; vB1 = *(const bf16x8*)(vp + D); }
        else    { vA0 = *(const bf16x8*)vp; vA1 = *(const bf16x8*)(vp + D); }
      }
    }
    if (!active) continue;
    // QK^T from Ks[bf]
    f32x4 sacc[2][4];
#pragma unroll
    for (int mi = 0; mi < 2; mi++)
#pragma unroll
      for (int n16 = 0; n16 < 4; n16++) sacc[mi][n16] = (f32x4){0.f, 0.f, 0.f, 0.f};
    {
      bf16x8 bk0[4], bk1[4];
#pragma unroll
      for (int n16 = 0; n16 < 4; n16++) {
        bk0[n16] = *(const bf16x8*)&Ks[bf][0][(n16 * 16 + col) * 32 + quad * 8];
        bk1[n16] = *(const bf16x8*)&Ks[bf][1][(n16 * 16 + col) * 32 + quad * 8];
      }
#pragma unroll
      for (int mi = 0; mi < 2; mi++)
#pragma unroll
        for (int n16 = 0; n16 < 4; n16++) {
          sacc[mi][n16] = __builtin_amdgcn_mfma_f32_16x16x32_bf16(aq[mi][0], bk0[n16], sacc[mi][n16], 0, 0, 0);
          sacc[mi][n16] = __builtin_amdgcn_mfma_f32_16x16x32_bf16(aq[mi][1], bk1[n16], sacc[mi][n16], 0, 0, 0);
        }
    }
    const bool full = (kt * 64 + 63) <= qw;  // wave-uniform: no masking
    // V fragments (shared across mi)
    bf16x8 bv[2][4];
#pragma unroll
    for (int kb = 0; kb < 2; kb++)
#pragma unroll
      for (int dg = 0; dg < 4; dg++) {
        int d3 = (dg * 2 + (col >> 3)) & 7;
        bv[kb][dg] = *(const bf16x8*)&Vt[bf][(dg * 16 + col) * 64 + (((kb * 4 + quad) ^ d3) << 3)];
      }
    // per-mi: exp -> Pw -> PV (same-wave LDS write->read, in-order, no barrier)
#pragma unroll
    for (int mi = 0; mi < 2; mi++) {
#pragma unroll
      for (int r = 0; r < 4; r++) {
        int row16 = quad * 4 + r;
        int qs = quad << 1;
#pragma unroll
        for (int n16 = 0; n16 < 4; n16++) {
          float p = EXP2F(sacc[mi][n16][r]);
          if (!full) {
            int kg = kt * 64 + n16 * 16 + col;
            p = (kg > qw + mi * 16 + row16) ? 0.f : p;
          }
          int kgl = n16 * 16 + col;
          int perm = ((kgl >> 3) ^ qs) & 7;
          Pw[wave][row16 * 64 + perm * 8 + (kgl & 7)] = (u16)(__float_as_uint(p) >> 16);
        }
      }
      int qs2 = ((col >> 2) & 3) << 1;
      bf16x8 ap0 = *(const bf16x8*)&Pw[wave][col * 64 + (((quad ^ qs2) & 7) << 3)];
      bf16x8 ap1 = *(const bf16x8*)&Pw[wave][col * 64 + ((((4 + quad) ^ qs2) & 7) << 3)];
#pragma unroll
      for (int dg = 0; dg < 4; dg++) {
        ao[mi][dg] = __builtin_amdgcn_mfma_f32_16x16x32_bf16(ap0, bv[0][dg], ao[mi][dg], 0, 0, 0);
        ao[mi][dg] = __builtin_amdgcn_mfma_f32_16x16x32_bf16(ap1, bv[1][dg], ao[mi][dg], 0, 0, 0);
      }
      lacc[mi] = __builtin_amdgcn_mfma_f32_16x16x32_bf16(ap0, bones, lacc[mi], 0, 0, 0);
      lacc[mi] = __builtin_amdgcn_mfma_f32_16x16x32_bf16(ap1, bones, lacc[mi], 0, 0, 0);
    }
  }
  // epilogue: normalize + write O
#pragma unroll
  for (int mi = 0; mi < 2; mi++)
#pragma unroll
    for (int r = 0; r < 4; r++) {
      float inv = 1.f / lacc[mi][r];
      int q = qw + mi * 16 + quad * 4 + r;
#pragma unroll
      for (int dg = 0; dg < 4; dg++)
        O[base + (size_t)q * D + dg * 16 + col] = f2bf(ao[mi][dg][r] * inv);
    }
}

extern "C" void kernel_launch(void* const* d_in, const int* in_sizes, int n_in,
                              void* d_out, int out_size, void* d_ws, size_t ws_size,
                              hipStream_t stream) {
  const float* x  = (const float*)d_in[0];
  const float* Wq = (const float*)d_in[1];
  const float* Wk = (const float*)d_in[2];
  const float* Wv = (const float*)d_in[3];
  const float* Wo = (const float*)d_in[4];

  u16* xb  = (u16*)d_ws;
  u16* wqb = xb + (size_t)M * D;
  u16* wkb = wqb + (size_t)D * D;
  u16* wvb = wkb + (size_t)D * D;
  u16* wob = wvb + (size_t)D * D;
  u16* Qb  = wob + (size_t)D * D;
  u16* Kb  = Qb + (size_t)M * D;
  u16* Vb  = Kb + (size_t)M * D;
  u16* Ab  = xb;  // x dead after projections

  cast_kernel<<<M * D / 1024, 256, 0, stream>>>(x, xb, M * D);
  CastArgs ca;
  ca.s[0] = Wq; ca.s[1] = Wk; ca.s[2] = Wv; ca.s[3] = Wo;
  ca.d[0] = wqb; ca.d[1] = wkb; ca.d[2] = wvb; ca.d[3] = wob;
  ca.sc[0] = 0.18033688011112042f;  // 0.125 * log2(e) folded into Wq
  ca.sc[1] = 1.f; ca.sc[2] = 1.f; ca.sc[3] = 1.f;
  cast4_kernel<<<4 * D * D / 1024, 256, 0, stream>>>(ca);

  QkvArgs qa;
  qa.bt[0] = wqb; qa.bt[1] = wkb; qa.bt[2] = wvb;
  qa.c[0] = Qb; qa.c[1] = Kb; qa.c[2] = Vb;
  gemm_qkv<<<dim3(24, M / 128), 256, 0, stream>>>(xb, qa);

  attn_kernel<<<dim3(Bb * H, 16), 256, 0, stream>>>(Qb, Kb, Vb, Ab);

  gemm_f32<<<dim3(D / 128, M / 128), 256, 0, stream>>>(Ab, wob, (float*)d_out);
}

// Round 7
// 281.130 us; speedup vs baseline: 1.8356x; 1.8356x over previous
//
#include <hip/hip_runtime.h>

typedef __attribute__((ext_vector_type(8))) short bf16x8;
typedef __attribute__((ext_vector_type(4))) float f32x4;
typedef unsigned int u32;
typedef unsigned short u16;

constexpr int Bb = 4, S = 2048, D = 1024, H = 16, DK = 64, M = Bb * S;

#if __has_builtin(__builtin_amdgcn_exp2f)
#define EXP2F __builtin_amdgcn_exp2f
#else
#define EXP2F exp2f
#endif

__device__ __forceinline__ u16 f2bf(float f) {
  u32 u = __float_as_uint(f);
  return (u16)((u + 0x7fffu + ((u >> 16) & 1u)) >> 16);
}

__device__ __forceinline__ void gld_lds16(const u16* g, u16* l) {
  __builtin_amdgcn_global_load_lds((const __attribute__((address_space(1))) u32*)g,
                                   (__attribute__((address_space(3))) u32*)l, 16, 0, 0);
}

__global__ void cast_kernel(const float* __restrict__ s, u16* __restrict__ d, int n) {
  int i = (blockIdx.x * blockDim.x + threadIdx.x) * 4;
  if (i >= n) return;
  float4 f = *(const float4*)(s + i);
  ushort4 o;
  o.x = f2bf(f.x); o.y = f2bf(f.y); o.z = f2bf(f.z); o.w = f2bf(f.w);
  *(ushort4*)(d + i) = o;
}

struct CastArgs { const float* s[4]; u16* d[4]; float sc[4]; };
__global__ void cast4_kernel(CastArgs a) {
  int i = (blockIdx.x * blockDim.x + threadIdx.x) * 4;
  int w = i >> 20;
  int off = i & ((1 << 20) - 1);
  float sc = a.sc[w];
  float4 f = *(const float4*)(a.s[w] + off);
  ushort4 o;
  o.x = f2bf(f.x * sc); o.y = f2bf(f.y * sc); o.z = f2bf(f.z * sc); o.w = f2bf(f.w * sc);
  *(ushort4*)(a.d[w] + off) = o;
}

// ---- GEMM core: C[m,n] = sum_k A[m,k]*Bt[n,k], 128x128 tile, BK=64 ----
template <bool OUTF32>
__device__ __forceinline__ void gemm_core(const u16* __restrict__ A,
                                          const u16* __restrict__ Bt,
                                          float* __restrict__ Cf, u16* __restrict__ Cb,
                                          int Nn, int Kk, int m0, int n0,
                                          u16* As, u16* Bs) {
  const int tid = threadIdx.x, wave = tid >> 6, lane = tid & 63;
  const int quad = lane >> 4, col = lane & 15;
  const int wm = wave >> 1, wn = wave & 1;

  f32x4 acc[4][4];
#pragma unroll
  for (int i = 0; i < 4; i++)
#pragma unroll
    for (int j = 0; j < 4; j++) acc[i][j] = (f32x4){0.f, 0.f, 0.f, 0.f};

  for (int k0 = 0; k0 < Kk; k0 += 64) {
#pragma unroll
    for (int j = 0; j < 4; j++) {
      int g = (wave * 4 + j) * 64;
      int gl = g + lane;
      int r = gl >> 3, sl = gl & 7;
      int kof = (sl ^ (r & 7)) * 8;
      const u16* ga = A + (size_t)(m0 + r) * Kk + k0 + kof;
      gld_lds16(ga, &As[g * 8]);
      const u16* gb = Bt + (size_t)(n0 + r) * Kk + k0 + kof;
      gld_lds16(gb, &Bs[g * 8]);
    }
    __syncthreads();
#pragma unroll
    for (int kb = 0; kb < 2; kb++) {
      bf16x8 af[4], bfr[4];
#pragma unroll
      for (int mi = 0; mi < 4; mi++) {
        int R = wm * 64 + mi * 16 + col;
        af[mi] = *(const bf16x8*)&As[R * 64 + (((kb * 4 + quad) ^ (R & 7)) << 3)];
      }
#pragma unroll
      for (int ni = 0; ni < 4; ni++) {
        int R = wn * 64 + ni * 16 + col;
        bfr[ni] = *(const bf16x8*)&Bs[R * 64 + (((kb * 4 + quad) ^ (R & 7)) << 3)];
      }
#pragma unroll
      for (int mi = 0; mi < 4; mi++)
#pragma unroll
        for (int ni = 0; ni < 4; ni++)
          acc[mi][ni] = __builtin_amdgcn_mfma_f32_16x16x32_bf16(af[mi], bfr[ni], acc[mi][ni], 0, 0, 0);
    }
    __syncthreads();
  }
#pragma unroll
  for (int mi = 0; mi < 4; mi++)
#pragma unroll
    for (int ni = 0; ni < 4; ni++)
#pragma unroll
      for (int r = 0; r < 4; r++) {
        int row = m0 + wm * 64 + mi * 16 + quad * 4 + r;
        int cc = n0 + wn * 64 + ni * 16 + col;
        float v = acc[mi][ni][r];
        if (OUTF32) Cf[(size_t)row * Nn + cc] = v;
        else Cb[(size_t)row * Nn + cc] = f2bf(v);
      }
}

struct QkvArgs { const u16* bt[3]; u16* c[3]; };
__global__ __launch_bounds__(256) void gemm_qkv(const u16* __restrict__ A, QkvArgs q) {
  __shared__ __align__(16) u16 As[128 * 64];
  __shared__ __align__(16) u16 Bs[128 * 64];
  int sel = blockIdx.x >> 3;
  int n0 = (blockIdx.x & 7) * 128, m0 = blockIdx.y * 128;
  gemm_core<false>(A, q.bt[sel], nullptr, q.c[sel], D, D, m0, n0, As, Bs);
}

__global__ __launch_bounds__(256) void gemm_f32(const u16* __restrict__ A,
                                                const u16* __restrict__ Bt,
                                                float* __restrict__ C) {
  __shared__ __align__(16) u16 As[128 * 64];
  __shared__ __align__(16) u16 Bs[128 * 64];
  gemm_core<true>(A, Bt, C, nullptr, D, D, blockIdx.y * 128, blockIdx.x * 128, As, Bs);
}

// ---- flash attention, causal ----
// One 128-row q-block per workgroup; grid (64 bh, 16) = 1024 blocks.
// y->qb map {a,7-a,8+a,15-a}: every CU's round-robin bundle = 68 iters.
// LDS 40KB; NO min-wave hint (round 6 post-mortem: launch_bounds(256,4)
// clamped VGPR to 64 -> 266MB scratch spills -> 3.5x regression).
__global__ __launch_bounds__(256) void attn_kernel(const u16* __restrict__ Q,
                                                   const u16* __restrict__ K,
                                                   const u16* __restrict__ V,
                                                   u16* __restrict__ O) {
  __shared__ __align__(16) u16 Ks[2][2][64 * 32];  // [buf][d-half][key*32+d]
  __shared__ __align__(16) u16 Vt[2][64 * 64];     // [buf] V^T [d][key-swizzled]
  __shared__ __align__(16) u16 Pw[4][16 * 64];     // per-wave per-mi P [q16][key-swz]
  const int tid = threadIdx.x, wave = tid >> 6, lane = tid & 63;
  const int quad = lane >> 4, col = lane & 15;
  const int bh = blockIdx.x, b = bh >> 4, h = bh & 15;
  const int ya = blockIdx.y & 3, yk = blockIdx.y >> 2;
  const int qb = (yk == 0) ? ya : (yk == 1) ? 7 - ya : (yk == 2) ? 8 + ya : 15 - ya;
  const size_t base = (size_t)b * S * D + h * DK;
  const int qw = qb * 128 + wave * 32;
  const int nkt = 2 * qb + 2;  // >= 2

  bf16x8 aq[2][2];
#pragma unroll
  for (int mi = 0; mi < 2; mi++)
#pragma unroll
    for (int kb = 0; kb < 2; kb++)
      aq[mi][kb] = *(const bf16x8*)(Q + base + (size_t)(qw + mi * 16 + col) * D + kb * 32 + quad * 8);

  f32x4 ao[2][4], lacc[2];
#pragma unroll
  for (int mi = 0; mi < 2; mi++) {
    lacc[mi] = (f32x4){0.f, 0.f, 0.f, 0.f};
#pragma unroll
    for (int dg = 0; dg < 4; dg++) ao[mi][dg] = (f32x4){0.f, 0.f, 0.f, 0.f};
  }
  bf16x8 bones;
#pragma unroll
  for (int e = 0; e < 8; e++) bones[e] = (short)0x3F80;  // bf16 1.0

  // V staging: thread handles keys (vk0, vk0+1) x 8 d's; packed u32 writes
  const int vk0 = (tid & 31) * 2;
  const int vdg = tid >> 5;

  bf16x8 vA0, vA1, vB0, vB1;
  {
    const u16* vp = V + base + (size_t)vk0 * D + vdg * 8;
    vA0 = *(const bf16x8*)vp; vA1 = *(const bf16x8*)(vp + D);
  }
  {  // DMA K(0) -> Ks[0]
    int c = tid, cb = wave * 64;
    const u16* g0 = K + base + (size_t)(c >> 2) * D + (c & 3) * 8;
    gld_lds16(g0, &Ks[0][0][cb * 8]);
    gld_lds16(g0 + 32, &Ks[0][1][cb * 8]);
  }
  auto vstage = [&](int buf, bf16x8 r0, bf16x8 r1) {
    int kgrp = vk0 >> 3, kin = vk0 & 7;
    int perm = (kgrp ^ vdg) & 7;
#pragma unroll
    for (int e = 0; e < 8; e++) {
      u32 val = ((u32)(u16)r0[e]) | ((u32)(u16)r1[e] << 16);
      *(u32*)&Vt[buf][(vdg * 8 + e) * 64 + perm * 8 + kin] = val;
    }
  };
  vstage(0, vA0, vA1);
  {  // V(1) -> B regs
    const u16* vp = V + base + (size_t)(64 + vk0) * D + vdg * 8;
    vB0 = *(const bf16x8*)vp; vB1 = *(const bf16x8*)(vp + D);
  }

  for (int kt = 0; kt < nkt; kt++) {
    const int bf = kt & 1, nb = bf ^ 1;
    __syncthreads();  // drains K(kt) DMA + V(kt+1) regs; publishes Vt[bf]
    const bool active = (kt * 64 <= qw + 31);  // wave-uniform
    if (kt + 1 < nkt) {
      {  // prefetch K(kt+1) -> Ks[nb] (a full iteration to land)
        int c = tid, cb = wave * 64;
        const u16* g0 = K + base + (size_t)((kt + 1) * 64 + (c >> 2)) * D + (c & 3) * 8;
        gld_lds16(g0, &Ks[nb][0][cb * 8]);
        gld_lds16(g0 + 32, &Ks[nb][1][cb * 8]);
      }
      vstage(nb, bf ? vA0 : vB0, bf ? vA1 : vB1);
      if (kt + 2 < nkt) {
        const u16* vp = V + base + (size_t)((kt + 2) * 64 + vk0) * D + vdg * 8;
        if (bf) { vB0 = *(const bf16x8*)vp; vB1 = *(const bf16x8*)(vp + D); }
        else    { vA0 = *(const bf16x8*)vp; vA1 = *(const bf16x8*)(vp + D); }
      }
    }
    if (!active) continue;
    // QK^T from Ks[bf]
    f32x4 sacc[2][4];
#pragma unroll
    for (int mi = 0; mi < 2; mi++)
#pragma unroll
      for (int n16 = 0; n16 < 4; n16++) sacc[mi][n16] = (f32x4){0.f, 0.f, 0.f, 0.f};
    {
      bf16x8 bk0[4], bk1[4];
#pragma unroll
      for (int n16 = 0; n16 < 4; n16++) {
        bk0[n16] = *(const bf16x8*)&Ks[bf][0][(n16 * 16 + col) * 32 + quad * 8];
        bk1[n16] = *(const bf16x8*)&Ks[bf][1][(n16 * 16 + col) * 32 + quad * 8];
      }
#pragma unroll
      for (int mi = 0; mi < 2; mi++)
#pragma unroll
        for (int n16 = 0; n16 < 4; n16++) {
          sacc[mi][n16] = __builtin_amdgcn_mfma_f32_16x16x32_bf16(aq[mi][0], bk0[n16], sacc[mi][n16], 0, 0, 0);
          sacc[mi][n16] = __builtin_amdgcn_mfma_f32_16x16x32_bf16(aq[mi][1], bk1[n16], sacc[mi][n16], 0, 0, 0);
        }
    }
    const bool full = (kt * 64 + 63) <= qw;  // wave-uniform: no masking
    // V fragments (shared across mi)
    bf16x8 bv[2][4];
#pragma unroll
    for (int kb = 0; kb < 2; kb++)
#pragma unroll
      for (int dg = 0; dg < 4; dg++) {
        int d3 = (dg * 2 + (col >> 3)) & 7;
        bv[kb][dg] = *(const bf16x8*)&Vt[bf][(dg * 16 + col) * 64 + (((kb * 4 + quad) ^ d3) << 3)];
      }
    // per-mi: exp -> Pw -> PV (same-wave LDS write->read, in-order, no barrier)
#pragma unroll
    for (int mi = 0; mi < 2; mi++) {
#pragma unroll
      for (int r = 0; r < 4; r++) {
        int row16 = quad * 4 + r;
        int qs = quad << 1;
#pragma unroll
        for (int n16 = 0; n16 < 4; n16++) {
          float p = EXP2F(sacc[mi][n16][r]);
          if (!full) {
            int kg = kt * 64 + n16 * 16 + col;
            p = (kg > qw + mi * 16 + row16) ? 0.f : p;
          }
          int kgl = n16 * 16 + col;
          int perm = ((kgl >> 3) ^ qs) & 7;
          Pw[wave][row16 * 64 + perm * 8 + (kgl & 7)] = (u16)(__float_as_uint(p) >> 16);
        }
      }
      int qs2 = ((col >> 2) & 3) << 1;
      bf16x8 ap0 = *(const bf16x8*)&Pw[wave][col * 64 + (((quad ^ qs2) & 7) << 3)];
      bf16x8 ap1 = *(const bf16x8*)&Pw[wave][col * 64 + ((((4 + quad) ^ qs2) & 7) << 3)];
#pragma unroll
      for (int dg = 0; dg < 4; dg++) {
        ao[mi][dg] = __builtin_amdgcn_mfma_f32_16x16x32_bf16(ap0, bv[0][dg], ao[mi][dg], 0, 0, 0);
        ao[mi][dg] = __builtin_amdgcn_mfma_f32_16x16x32_bf16(ap1, bv[1][dg], ao[mi][dg], 0, 0, 0);
      }
      lacc[mi] = __builtin_amdgcn_mfma_f32_16x16x32_bf16(ap0, bones, lacc[mi], 0, 0, 0);
      lacc[mi] = __builtin_amdgcn_mfma_f32_16x16x32_bf16(ap1, bones, lacc[mi], 0, 0, 0);
    }
  }
  // epilogue: normalize + write O
#pragma unroll
  for (int mi = 0; mi < 2; mi++)
#pragma unroll
    for (int r = 0; r < 4; r++) {
      float inv = 1.f / lacc[mi][r];
      int q = qw + mi * 16 + quad * 4 + r;
#pragma unroll
      for (int dg = 0; dg < 4; dg++)
        O[base + (size_t)q * D + dg * 16 + col] = f2bf(ao[mi][dg][r] * inv);
    }
}

extern "C" void kernel_launch(void* const* d_in, const int* in_sizes, int n_in,
                              void* d_out, int out_size, void* d_ws, size_t ws_size,
                              hipStream_t stream) {
  const float* x  = (const float*)d_in[0];
  const float* Wq = (const float*)d_in[1];
  const float* Wk = (const float*)d_in[2];
  const float* Wv = (const float*)d_in[3];
  const float* Wo = (const float*)d_in[4];

  u16* xb  = (u16*)d_ws;
  u16* wqb = xb + (size_t)M * D;
  u16* wkb = wqb + (size_t)D * D;
  u16* wvb = wkb + (size_t)D * D;
  u16* wob = wvb + (size_t)D * D;
  u16* Qb  = wob + (size_t)D * D;
  u16* Kb  = Qb + (size_t)M * D;
  u16* Vb  = Kb + (size_t)M * D;
  u16* Ab  = xb;  // x dead after projections

  cast_kernel<<<M * D / 1024, 256, 0, stream>>>(x, xb, M * D);
  CastArgs ca;
  ca.s[0] = Wq; ca.s[1] = Wk; ca.s[2] = Wv; ca.s[3] = Wo;
  ca.d[0] = wqb; ca.d[1] = wkb; ca.d[2] = wvb; ca.d[3] = wob;
  ca.sc[0] = 0.18033688011112042f;  // 0.125 * log2(e) folded into Wq
  ca.sc[1] = 1.f; ca.sc[2] = 1.f; ca.sc[3] = 1.f;
  cast4_kernel<<<4 * D * D / 1024, 256, 0, stream>>>(ca);

  QkvArgs qa;
  qa.bt[0] = wqb; qa.bt[1] = wkb; qa.bt[2] = wvb;
  qa.c[0] = Qb; qa.c[1] = Kb; qa.c[2] = Vb;
  gemm_qkv<<<dim3(24, M / 128), 256, 0, stream>>>(xb, qa);

  attn_kernel<<<dim3(Bb * H, 16), 256, 0, stream>>>(Qb, Kb, Vb, Ab);

  gemm_f32<<<dim3(D / 128, M / 128), 256, 0, stream>>>(Ab, wob, (float*)d_out);
}

// Round 8
// 277.379 us; speedup vs baseline: 1.8604x; 1.0135x over previous
//
#include <hip/hip_runtime.h>

typedef __attribute__((ext_vector_type(8))) short bf16x8;
typedef __attribute__((ext_vector_type(4))) float f32x4;
typedef unsigned int u32;
typedef unsigned short u16;

constexpr int Bb = 4, S = 2048, D = 1024, H = 16, DK = 64, M = Bb * S;

#if __has_builtin(__builtin_amdgcn_exp2f)
#define EXP2F __builtin_amdgcn_exp2f
#else
#define EXP2F exp2f
#endif

__device__ __forceinline__ u16 f2bf(float f) {
  u32 u = __float_as_uint(f);
  return (u16)((u + 0x7fffu + ((u >> 16) & 1u)) >> 16);
}
__device__ __forceinline__ float bf2f(u16 x) {
  return __uint_as_float(((u32)x) << 16);
}

__device__ __forceinline__ void gld_lds16(const u16* g, u16* l) {
  __builtin_amdgcn_global_load_lds((const __attribute__((address_space(1))) u32*)g,
                                   (__attribute__((address_space(3))) u32*)l, 16, 0, 0);
}

__global__ void cast_kernel(const float* __restrict__ s, u16* __restrict__ d, int n) {
  int i = (blockIdx.x * blockDim.x + threadIdx.x) * 4;
  if (i >= n) return;
  float4 f = *(const float4*)(s + i);
  ushort4 o;
  o.x = f2bf(f.x); o.y = f2bf(f.y); o.z = f2bf(f.z); o.w = f2bf(f.w);
  *(ushort4*)(d + i) = o;
}

struct CastArgs { const float* s[4]; u16* d[4]; float sc[4]; };
__global__ void cast4_kernel(CastArgs a) {
  int i = (blockIdx.x * blockDim.x + threadIdx.x) * 4;
  int w = i >> 20;
  int off = i & ((1 << 20) - 1);
  float sc = a.sc[w];
  float4 f = *(const float4*)(a.s[w] + off);
  ushort4 o;
  o.x = f2bf(f.x * sc); o.y = f2bf(f.y * sc); o.z = f2bf(f.z * sc); o.w = f2bf(f.w * sc);
  *(ushort4*)(a.d[w] + off) = o;
}

// ---- GEMM core: C[m,n] = sum_k A[m,k]*Bt[n,k], 128x128 tile, BK=64 ----
template <bool OUTF32>
__device__ __forceinline__ void gemm_core(const u16* __restrict__ A,
                                          const u16* __restrict__ Bt,
                                          float* __restrict__ Cf, u16* __restrict__ Cb,
                                          int Nn, int Kk, int m0, int n0,
                                          u16* As, u16* Bs) {
  const int tid = threadIdx.x, wave = tid >> 6, lane = tid & 63;
  const int quad = lane >> 4, col = lane & 15;
  const int wm = wave >> 1, wn = wave & 1;

  f32x4 acc[4][4];
#pragma unroll
  for (int i = 0; i < 4; i++)
#pragma unroll
    for (int j = 0; j < 4; j++) acc[i][j] = (f32x4){0.f, 0.f, 0.f, 0.f};

  for (int k0 = 0; k0 < Kk; k0 += 64) {
#pragma unroll
    for (int j = 0; j < 4; j++) {
      int g = (wave * 4 + j) * 64;
      int gl = g + lane;
      int r = gl >> 3, sl = gl & 7;
      int kof = (sl ^ (r & 7)) * 8;
      const u16* ga = A + (size_t)(m0 + r) * Kk + k0 + kof;
      gld_lds16(ga, &As[g * 8]);
      const u16* gb = Bt + (size_t)(n0 + r) * Kk + k0 + kof;
      gld_lds16(gb, &Bs[g * 8]);
    }
    __syncthreads();
#pragma unroll
    for (int kb = 0; kb < 2; kb++) {
      bf16x8 af[4], bfr[4];
#pragma unroll
      for (int mi = 0; mi < 4; mi++) {
        int R = wm * 64 + mi * 16 + col;
        af[mi] = *(const bf16x8*)&As[R * 64 + (((kb * 4 + quad) ^ (R & 7)) << 3)];
      }
#pragma unroll
      for (int ni = 0; ni < 4; ni++) {
        int R = wn * 64 + ni * 16 + col;
        bfr[ni] = *(const bf16x8*)&Bs[R * 64 + (((kb * 4 + quad) ^ (R & 7)) << 3)];
      }
#pragma unroll
      for (int mi = 0; mi < 4; mi++)
#pragma unroll
        for (int ni = 0; ni < 4; ni++)
          acc[mi][ni] = __builtin_amdgcn_mfma_f32_16x16x32_bf16(af[mi], bfr[ni], acc[mi][ni], 0, 0, 0);
    }
    __syncthreads();
  }
#pragma unroll
  for (int mi = 0; mi < 4; mi++)
#pragma unroll
    for (int ni = 0; ni < 4; ni++)
#pragma unroll
      for (int r = 0; r < 4; r++) {
        int row = m0 + wm * 64 + mi * 16 + quad * 4 + r;
        int cc = n0 + wn * 64 + ni * 16 + col;
        float v = acc[mi][ni][r];
        if (OUTF32) Cf[(size_t)row * Nn + cc] = v;
        else Cb[(size_t)row * Nn + cc] = f2bf(v);
      }
}

struct QkvArgs { const u16* bt[3]; u16* c[3]; };
__global__ __launch_bounds__(256) void gemm_qkv(const u16* __restrict__ A, QkvArgs q) {
  __shared__ __align__(16) u16 As[128 * 64];
  __shared__ __align__(16) u16 Bs[128 * 64];
  int sel = blockIdx.x >> 3;
  int n0 = (blockIdx.x & 7) * 128, m0 = blockIdx.y * 128;
  gemm_core<false>(A, q.bt[sel], nullptr, q.c[sel], D, D, m0, n0, As, Bs);
}

__global__ __launch_bounds__(256) void gemm_f32(const u16* __restrict__ A,
                                                const u16* __restrict__ Bt,
                                                float* __restrict__ C) {
  __shared__ __align__(16) u16 As[128 * 64];
  __shared__ __align__(16) u16 Bs[128 * 64];
  gemm_core<true>(A, Bt, C, nullptr, D, D, blockIdx.y * 128, blockIdx.x * 128, As, Bs);
}

// ---- flash attention, causal, uniform-work key-split ----
// Pair (qb_hi=15-p, qb_lo=p). role0: kt 0..16 of qb_hi (17 tiles).
// role1: kt 17..Th-1 of qb_hi (15-2p) + all of qb_lo (2p+2) = 17 tiles.
// Every WG exactly 17 k-tiles -> grid 64x16 = 1024 uniform blocks = 4/CU
// steadily resident (per-iter stalls overlap across blocks).
// No-max softmax => O_unnorm/l are associative sums: split-qb partials
// (bf16 O + fp32 l) land in d_out scratch; norm_kernel merges into Ab.
__global__ __launch_bounds__(256) void attn_kernel(const u16* __restrict__ Q,
                                                   const u16* __restrict__ K,
                                                   const u16* __restrict__ V,
                                                   u16* __restrict__ O,
                                                   u16* __restrict__ Po,
                                                   float* __restrict__ Lf) {
  __shared__ __align__(16) u16 Ks[2][2][64 * 32];  // [buf][d-half][key*32+d]
  __shared__ __align__(16) u16 Vt[2][64 * 64];     // [buf] V^T [d][key-swizzled]
  __shared__ __align__(16) u16 Pw[4][16 * 64];     // per-wave per-mi P [q16][key-swz]
  const int tid = threadIdx.x, wave = tid >> 6, lane = tid & 63;
  const int quad = lane >> 4, col = lane & 15;
  const int bh = blockIdx.x, b = bh >> 4, h = bh & 15;
  const int j = blockIdx.y, p = j >> 1, role = j & 1;
  const int qbh = 15 - p, Th = 2 * qbh + 2;
  const size_t base = (size_t)b * S * D + h * DK;

  int segQb[2], segK0[2], segK1[2], nseg;
  if (role == 0) {
    nseg = 1; segQb[0] = qbh; segK0[0] = 0; segK1[0] = 17;
  } else {
    nseg = 2;
    segQb[0] = qbh; segK0[0] = 17; segK1[0] = Th;
    segQb[1] = p;   segK0[1] = 0;  segK1[1] = 2 * p + 2;
  }

  bf16x8 bones;
#pragma unroll
  for (int e = 0; e < 8; e++) bones[e] = (short)0x3F80;  // bf16 1.0

  // V staging: thread handles keys (vk0, vk0+1) x 8 d's; packed u32 writes
  const int vk0 = (tid & 31) * 2;
  const int vdg = tid >> 5;

  for (int s = 0; s < nseg; s++) {
    const int sqb = segQb[s], k0s = segK0[s], k1s = segK1[s];
    const int qw = sqb * 128 + wave * 32;
    const bool partial = (sqb >= 8);  // split qb -> partial output

    bf16x8 aq[2][2];
#pragma unroll
    for (int mi = 0; mi < 2; mi++)
#pragma unroll
      for (int kb = 0; kb < 2; kb++)
        aq[mi][kb] = *(const bf16x8*)(Q + base + (size_t)(qw + mi * 16 + col) * D + kb * 32 + quad * 8);

    f32x4 ao[2][4], lacc[2];
#pragma unroll
    for (int mi = 0; mi < 2; mi++) {
      lacc[mi] = (f32x4){0.f, 0.f, 0.f, 0.f};
#pragma unroll
      for (int dg = 0; dg < 4; dg++) ao[mi][dg] = (f32x4){0.f, 0.f, 0.f, 0.f};
    }

    bf16x8 vA0, vA1, vB0, vB1;
    {
      const u16* vp = V + base + (size_t)(k0s * 64 + vk0) * D + vdg * 8;
      vA0 = *(const bf16x8*)vp; vA1 = *(const bf16x8*)(vp + D);
    }
    __syncthreads();  // previous segment's LDS readers done before restaging
    {  // DMA K(k0s) -> Ks[0]
      int c = tid, cb = wave * 64;
      const u16* g0 = K + base + (size_t)(k0s * 64 + (c >> 2)) * D + (c & 3) * 8;
      gld_lds16(g0, &Ks[0][0][cb * 8]);
      gld_lds16(g0 + 32, &Ks[0][1][cb * 8]);
    }
    auto vstage = [&](int buf, bf16x8 r0, bf16x8 r1) {
      int kgrp = vk0 >> 3, kin = vk0 & 7;
      int perm = (kgrp ^ vdg) & 7;
#pragma unroll
      for (int e = 0; e < 8; e++) {
        u32 val = ((u32)(u16)r0[e]) | ((u32)(u16)r1[e] << 16);
        *(u32*)&Vt[buf][(vdg * 8 + e) * 64 + perm * 8 + kin] = val;
      }
    };
    vstage(0, vA0, vA1);
    if (k0s + 1 < k1s) {  // V(k0s+1) -> B regs
      const u16* vp = V + base + (size_t)((k0s + 1) * 64 + vk0) * D + vdg * 8;
      vB0 = *(const bf16x8*)vp; vB1 = *(const bf16x8*)(vp + D);
    }

    for (int kt = k0s; kt < k1s; kt++) {
      const int ib = (kt - k0s) & 1, nb = ib ^ 1;
      __syncthreads();  // drains K(kt) DMA + V(kt+1) regs; publishes Vt[ib]
      const bool active = (kt * 64 <= qw + 31);  // wave-uniform
      if (kt + 1 < k1s) {
        {  // prefetch K(kt+1) -> Ks[nb] (a full iteration to land)
          int c = tid, cb = wave * 64;
          const u16* g0 = K + base + (size_t)((kt + 1) * 64 + (c >> 2)) * D + (c & 3) * 8;
          gld_lds16(g0, &Ks[nb][0][cb * 8]);
          gld_lds16(g0 + 32, &Ks[nb][1][cb * 8]);
        }
        vstage(nb, ib ? vA0 : vB0, ib ? vA1 : vB1);
        if (kt + 2 < k1s) {
          const u16* vp = V + base + (size_t)((kt + 2) * 64 + vk0) * D + vdg * 8;
          if (ib) { vB0 = *(const bf16x8*)vp; vB1 = *(const bf16x8*)(vp + D); }
          else    { vA0 = *(const bf16x8*)vp; vA1 = *(const bf16x8*)(vp + D); }
        }
      }
      if (!active) continue;
      // QK^T from Ks[ib]
      f32x4 sacc[2][4];
#pragma unroll
      for (int mi = 0; mi < 2; mi++)
#pragma unroll
        for (int n16 = 0; n16 < 4; n16++) sacc[mi][n16] = (f32x4){0.f, 0.f, 0.f, 0.f};
      {
        bf16x8 bk0[4], bk1[4];
#pragma unroll
        for (int n16 = 0; n16 < 4; n16++) {
          bk0[n16] = *(const bf16x8*)&Ks[ib][0][(n16 * 16 + col) * 32 + quad * 8];
          bk1[n16] = *(const bf16x8*)&Ks[ib][1][(n16 * 16 + col) * 32 + quad * 8];
        }
#pragma unroll
        for (int mi = 0; mi < 2; mi++)
#pragma unroll
          for (int n16 = 0; n16 < 4; n16++) {
            sacc[mi][n16] = __builtin_amdgcn_mfma_f32_16x16x32_bf16(aq[mi][0], bk0[n16], sacc[mi][n16], 0, 0, 0);
            sacc[mi][n16] = __builtin_amdgcn_mfma_f32_16x16x32_bf16(aq[mi][1], bk1[n16], sacc[mi][n16], 0, 0, 0);
          }
      }
      const bool full = (kt * 64 + 63) <= qw;  // wave-uniform: no masking
      // V fragments (shared across mi)
      bf16x8 bv[2][4];
#pragma unroll
      for (int kb = 0; kb < 2; kb++)
#pragma unroll
        for (int dg = 0; dg < 4; dg++) {
          int d3 = (dg * 2 + (col >> 3)) & 7;
          bv[kb][dg] = *(const bf16x8*)&Vt[ib][(dg * 16 + col) * 64 + (((kb * 4 + quad) ^ d3) << 3)];
        }
      // per-mi: exp -> Pw -> PV (same-wave LDS write->read, in-order, no barrier)
#pragma unroll
      for (int mi = 0; mi < 2; mi++) {
#pragma unroll
        for (int r = 0; r < 4; r++) {
          int row16 = quad * 4 + r;
          int qs = quad << 1;
#pragma unroll
          for (int n16 = 0; n16 < 4; n16++) {
            float pv = EXP2F(sacc[mi][n16][r]);
            if (!full) {
              int kg = kt * 64 + n16 * 16 + col;
              pv = (kg > qw + mi * 16 + row16) ? 0.f : pv;
            }
            int kgl = n16 * 16 + col;
            int perm = ((kgl >> 3) ^ qs) & 7;
            Pw[wave][row16 * 64 + perm * 8 + (kgl & 7)] = (u16)(__float_as_uint(pv) >> 16);
          }
        }
        int qs2 = ((col >> 2) & 3) << 1;
        bf16x8 ap0 = *(const bf16x8*)&Pw[wave][col * 64 + (((quad ^ qs2) & 7) << 3)];
        bf16x8 ap1 = *(const bf16x8*)&Pw[wave][col * 64 + ((((4 + quad) ^ qs2) & 7) << 3)];
#pragma unroll
        for (int dg = 0; dg < 4; dg++) {
          ao[mi][dg] = __builtin_amdgcn_mfma_f32_16x16x32_bf16(ap0, bv[0][dg], ao[mi][dg], 0, 0, 0);
          ao[mi][dg] = __builtin_amdgcn_mfma_f32_16x16x32_bf16(ap1, bv[1][dg], ao[mi][dg], 0, 0, 0);
        }
        lacc[mi] = __builtin_amdgcn_mfma_f32_16x16x32_bf16(ap0, bones, lacc[mi], 0, 0, 0);
        lacc[mi] = __builtin_amdgcn_mfma_f32_16x16x32_bf16(ap1, bones, lacc[mi], 0, 0, 0);
      }
    }
    // epilogue
    if (!partial) {
#pragma unroll
      for (int mi = 0; mi < 2; mi++)
#pragma unroll
        for (int r = 0; r < 4; r++) {
          float inv = 1.f / lacc[mi][r];
          int q = qw + mi * 16 + quad * 4 + r;
#pragma unroll
          for (int dg = 0; dg < 4; dg++)
            O[base + (size_t)q * D + dg * 16 + col] = f2bf(ao[mi][dg][r] * inv);
        }
    } else {
      int slot = role * 512 + bh * 8 + p;
      u16* po = Po + (size_t)slot * 8192;   // [128][64]
      float* lf = Lf + slot * 128;
#pragma unroll
      for (int mi = 0; mi < 2; mi++)
#pragma unroll
        for (int r = 0; r < 4; r++) {
          int row = wave * 32 + mi * 16 + quad * 4 + r;
#pragma unroll
          for (int dg = 0; dg < 4; dg++)
            po[row * 64 + dg * 16 + col] = f2bf(ao[mi][dg][r]);
          if (col == 0) lf[row] = lacc[mi][r];
        }
    }
  }
}

// merge the two key-split partials of each hi q-block and write bf16 into Ab
__global__ __launch_bounds__(256) void norm_kernel(const u16* __restrict__ Po,
                                                   const float* __restrict__ Lf,
                                                   u16* __restrict__ Ab) {
  int t = blockIdx.x * 256 + threadIdx.x;  // 64*8*128*16 = 1,048,576
  int c4 = t & 15, r = (t >> 4) & 127, pp = (t >> 11) & 7, bh = t >> 14;
  int slot = bh * 8 + pp;
  const u16* p0 = Po + (size_t)slot * 8192 + r * 64 + c4 * 4;
  const u16* p1 = Po + (size_t)(512 + slot) * 8192 + r * 64 + c4 * 4;
  float l = Lf[slot * 128 + r] + Lf[(512 + slot) * 128 + r];
  float inv = 1.f / l;
  ushort4 a = *(const ushort4*)p0, c = *(const ushort4*)p1;
  ushort4 o;
  o.x = f2bf((bf2f(a.x) + bf2f(c.x)) * inv);
  o.y = f2bf((bf2f(a.y) + bf2f(c.y)) * inv);
  o.z = f2bf((bf2f(a.z) + bf2f(c.z)) * inv);
  o.w = f2bf((bf2f(a.w) + bf2f(c.w)) * inv);
  int b = bh >> 4, h = bh & 15, qbh = 15 - pp;
  u16* dst = Ab + (size_t)b * S * D + (size_t)(qbh * 128 + r) * D + h * DK + c4 * 4;
  *(ushort4*)dst = o;
}

extern "C" void kernel_launch(void* const* d_in, const int* in_sizes, int n_in,
                              void* d_out, int out_size, void* d_ws, size_t ws_size,
                              hipStream_t stream) {
  const float* x  = (const float*)d_in[0];
  const float* Wq = (const float*)d_in[1];
  const float* Wk = (const float*)d_in[2];
  const float* Wv = (const float*)d_in[3];
  const float* Wo = (const float*)d_in[4];

  u16* xb  = (u16*)d_ws;
  u16* wqb = xb + (size_t)M * D;
  u16* wkb = wqb + (size_t)D * D;
  u16* wvb = wkb + (size_t)D * D;
  u16* wob = wvb + (size_t)D * D;
  u16* Qb  = wob + (size_t)D * D;
  u16* Kb  = Qb + (size_t)M * D;
  u16* Vb  = Kb + (size_t)M * D;
  u16* Ab  = xb;  // x dead after projections

  // key-split partial scratch carved out of d_out (overwritten by gemm_f32):
  // Po: 1024 slots x 128x64 bf16 = 16.8 MB; Lf: 1024 x 128 fp32 = 0.5 MB
  u16* Po = (u16*)d_out;
  float* Lf = (float*)(Po + (size_t)1024 * 8192);

  cast_kernel<<<M * D / 1024, 256, 0, stream>>>(x, xb, M * D);
  CastArgs ca;
  ca.s[0] = Wq; ca.s[1] = Wk; ca.s[2] = Wv; ca.s[3] = Wo;
  ca.d[0] = wqb; ca.d[1] = wkb; ca.d[2] = wvb; ca.d[3] = wob;
  ca.sc[0] = 0.18033688011112042f;  // 0.125 * log2(e) folded into Wq
  ca.sc[1] = 1.f; ca.sc[2] = 1.f; ca.sc[3] = 1.f;
  cast4_kernel<<<4 * D * D / 1024, 256, 0, stream>>>(ca);

  QkvArgs qa;
  qa.bt[0] = wqb; qa.bt[1] = wkb; qa.bt[2] = wvb;
  qa.c[0] = Qb; qa.c[1] = Kb; qa.c[2] = Vb;
  gemm_qkv<<<dim3(24, M / 128), 256, 0, stream>>>(xb, qa);

  attn_kernel<<<dim3(Bb * H, 16), 256, 0, stream>>>(Qb, Kb, Vb, Ab, Po, Lf);
  norm_kernel<<<4096, 256, 0, stream>>>(Po, Lf, Ab);

  gemm_f32<<<dim3(D / 128, M / 128), 256, 0, stream>>>(Ab, wob, (float*)d_out);
}